// Round 1
// baseline (206.599 us; speedup 1.0000x reference)
//
#include <hip/hip_runtime.h>
#include <hip/hip_bf16.h>

#define NROWS 262144
#define B1 512
// exp(x*0.125) == exp2(x * 0.125*log2(e))
#define CL 0.18033688011112042f

__device__ __forceinline__ float rl(float v, int lane) {
    return __uint_as_float(__builtin_amdgcn_readlane(__float_as_uint(v), lane));
}

// K1: each block handles 512 contiguous rows; produces partial ctx[64][64]
// (ctx = k_softmax^T @ V) and partial column-sums of exp(Q/8).
__global__ __launch_bounds__(512) void k1_stats(const float* __restrict__ Q,
                                                const float* __restrict__ K,
                                                const float* __restrict__ V,
                                                float* __restrict__ ctx_part,  // [B1][4096]
                                                float* __restrict__ qs_part)   // [B1][64]
{
    const int tid  = threadIdx.x;
    const int lane = tid & 63;
    const int wid  = tid >> 6;          // 8 waves
    const int base = blockIdx.x * 512;

    float ctx[64];
#pragma unroll
    for (int c = 0; c < 64; ++c) ctx[c] = 0.f;
    float qs = 0.f;

    for (int it = 0; it < 64; ++it) {
        const int i = base + it * 8 + wid;
        const float kraw = K[i * 64 + lane];
        const float vraw = V[i * 64 + lane];
        const float qraw = Q[i * 64 + lane];
        float e = exp2f(kraw * CL);          // K row softmax, no max needed (bounded args)
        float s = e;
#pragma unroll
        for (int m = 1; m < 64; m <<= 1) s += __shfl_xor(s, m);
        e *= __builtin_amdgcn_rcpf(s);       // e = kk[i][lane]
        qs += exp2f(qraw * CL);              // column-sum partial (lane = column)
        // rank-1 update: ctx[c][v=lane] += kk[i][c] * V[i][lane]
#pragma unroll
        for (int c = 0; c < 64; ++c)
            ctx[c] = fmaf(rl(e, c), vraw, ctx[c]);
    }

    __shared__ float ctxs[64 * 64];
    __shared__ float qsl[8 * 64];
    qsl[wid * 64 + lane] = qs;
    // fixed-order cross-wave ctx reduce (deterministic)
    for (int w = 0; w < 8; ++w) {
        if (wid == w) {
            if (w == 0) {
#pragma unroll
                for (int c = 0; c < 64; ++c) ctxs[c * 64 + lane] = ctx[c];
            } else {
#pragma unroll
                for (int c = 0; c < 64; ++c) ctxs[c * 64 + lane] += ctx[c];
            }
        }
        __syncthreads();
    }
    for (int e2 = tid; e2 < 4096; e2 += 512)
        ctx_part[blockIdx.x * 4096 + e2] = ctxs[e2];
    if (tid < 64) {
        float q8 = 0.f;
#pragma unroll
        for (int w = 0; w < 8; ++w) q8 += qsl[w * 64 + tid];
        qs_part[blockIdx.x * 64 + tid] = q8;
    }
}

// K2a: reduce column-sum partials -> inv_colsum[64]
__global__ void k2a(const float* __restrict__ qs_part, float* __restrict__ inv_cs) {
    const int c = threadIdx.x; // 64 threads
    float s = 0.f;
    for (int b = 0; b < B1; ++b) s += qs_part[b * 64 + c];
    inv_cs[c] = 1.0f / s;
}

// K2b: reduce ctx partials, scale row c by inv_colsum[c] -> ctx_final[64][64]
__global__ __launch_bounds__(256) void k2b(const float* __restrict__ ctx_part,
                                           const float* __restrict__ inv_cs,
                                           float* __restrict__ ctx_final) {
    const int c = blockIdx.x;        // 64 blocks
    const int v = threadIdx.x & 63;
    const int g = threadIdx.x >> 6;  // 0..3
    float s = 0.f;
    for (int b = g; b < B1; b += 4) s += ctx_part[(size_t)b * 4096 + c * 64 + v];
    __shared__ float red[4][64];
    red[g][v] = s;
    __syncthreads();
    if (threadIdx.x < 64) {
        float t = (red[0][v] + red[1][v]) + (red[2][v] + red[3][v]);
        ctx_final[c * 64 + v] = t * inv_cs[c];
    }
}

// K3: out[i][v] = sum_c exp2(Q[i][c]*CL) * ctx_final[c][v]
__global__ __launch_bounds__(256) void k3_out(const float* __restrict__ Q,
                                              const float* __restrict__ ctx_final,
                                              float* __restrict__ out) {
    const int tid  = threadIdx.x;
    const int lane = tid & 63;
    const int wid  = tid >> 6;      // 4 waves
    const int base = blockIdx.x * 256;

    float ctxp[64];
#pragma unroll
    for (int c = 0; c < 64; ++c) ctxp[c] = ctx_final[c * 64 + lane];

    for (int it = 0; it < 64; it += 2) {
        const int i0 = base + (it + 0) * 4 + wid;
        const int i1 = base + (it + 1) * 4 + wid;
        const float q0 = exp2f(Q[i0 * 64 + lane] * CL);
        const float q1 = exp2f(Q[i1 * 64 + lane] * CL);
        float o0 = 0.f, o1 = 0.f;
#pragma unroll
        for (int c = 0; c < 64; ++c) {
            o0 = fmaf(rl(q0, c), ctxp[c], o0);
            o1 = fmaf(rl(q1, c), ctxp[c], o1);
        }
        out[i0 * 64 + lane] = o0;
        out[i1 * 64 + lane] = o1;
    }
}

extern "C" void kernel_launch(void* const* d_in, const int* in_sizes, int n_in,
                              void* d_out, int out_size, void* d_ws, size_t ws_size,
                              hipStream_t stream) {
    const float* Q = (const float*)d_in[0];
    const float* K = (const float*)d_in[1];
    const float* V = (const float*)d_in[2];
    float* out = (float*)d_out;

    // workspace layout
    const size_t n_ctx_part = (size_t)B1 * 4096;
    const size_t n_qs_part  = (size_t)B1 * 64;
    const size_t need_full  = (n_ctx_part + n_qs_part + 64 + 4096) * sizeof(float);

    float *ctx_part, *qs_part, *inv_cs, *ctx_final;
    if (ws_size >= need_full) {
        float* w = (float*)d_ws;
        ctx_part  = w;                      w += n_ctx_part;
        qs_part   = w;                      w += n_qs_part;
        inv_cs    = w;                      w += 64;
        ctx_final = w;
    } else {
        // ctx partials (8 MB) live in d_out scratch (fully overwritten by k3 later)
        ctx_part  = out;
        float* w  = (float*)d_ws;
        qs_part   = w;                      w += n_qs_part;
        inv_cs    = w;                      w += 64;
        ctx_final = w;
    }

    k1_stats<<<B1, 512, 0, stream>>>(Q, K, V, ctx_part, qs_part);
    k2a<<<1, 64, 0, stream>>>(qs_part, inv_cs);
    k2b<<<64, 256, 0, stream>>>(ctx_part, inv_cs, ctx_final);
    k3_out<<<NROWS / 256, 256, 0, stream>>>(Q, ctx_final, out);
}

// Round 2
// 201.929 us; speedup vs baseline: 1.0231x; 1.0231x over previous
//
#include <hip/hip_runtime.h>
#include <hip/hip_bf16.h>

#define NROWS 262144
#define B1 1024            // k1 blocks
#define RPB 256            // rows per k1 block
// exp(x*0.125) == exp2(x * 0.125*log2(e))
#define CL 0.18033688011112042f

typedef __attribute__((ext_vector_type(8))) short s8v;   // 8 bf16 (4 VGPRs)
typedef __attribute__((ext_vector_type(4))) float f4v;   // MFMA acc

__device__ __forceinline__ ushort f2bf(float x) {        // RNE float->bf16 bits
    unsigned u = __float_as_uint(x);
    u += 0x7FFF + ((u >> 16) & 1);
    return (ushort)(u >> 16);
}

// K1: per block 256 rows. kk = rowsoftmax(K/8) and V staged transposed (bf16,
// XOR-swizzled) in LDS; ctx_part = kk^T @ V via MFMA (each wave owns 2 of the
// 16 16x16 tiles). Also qs_part = partial column sums of exp2(Q*CL).
__global__ __launch_bounds__(512) void k1_stats(const float* __restrict__ Q,
                                                const float* __restrict__ K,
                                                const float* __restrict__ V,
                                                float* __restrict__ ctx_part,  // [B1][4096]
                                                float* __restrict__ qs_part)   // [B1][64]
{
    const int tid  = threadIdx.x;
    const int lane = tid & 63;
    const int wid  = tid >> 6;          // 8 waves
    const int base = blockIdx.x * RPB;

    __shared__ ushort kkT[64 * 64];     // [col c][row r] bf16, swizzled 16B granules
    __shared__ ushort vT [64 * 64];     // [col v][row r]
    __shared__ float  qsl[8 * 64];

    const int cb  = wid >> 1;           // ctx row-block (c)
    const int vb0 = (wid & 1) * 2;      // ctx col-blocks vb0, vb0+1
    f4v acc0 = {0.f, 0.f, 0.f, 0.f};
    f4v acc1 = {0.f, 0.f, 0.f, 0.f};
    float qs = 0.f;

    // write: this wave's 8 rows form LDS granule 'wid' of every column (lane)
    const unsigned wr_off = (unsigned)lane * 128u + (unsigned)((wid ^ (lane & 7)) << 4);
    const int li = lane & 15, g = lane >> 4;

    for (int ch = 0; ch < RPB / 64; ++ch) {
        float kk[8], vv[8];
#pragma unroll
        for (int i = 0; i < 8; ++i) {
            const int row = base + ch * 64 + wid * 8 + i;
            const float kraw = K[row * 64 + lane];
            float e = exp2f(kraw * CL);          // args bounded, no max needed
            float s = e;
#pragma unroll
            for (int m = 1; m < 64; m <<= 1) s += __shfl_xor(s, m);
            kk[i] = e * __builtin_amdgcn_rcpf(s);
            vv[i] = V[row * 64 + lane];
            qs += exp2f(Q[row * 64 + lane] * CL);
        }
        s8v kvp, vvp;
#pragma unroll
        for (int i = 0; i < 8; ++i) {
            kvp[i] = (short)f2bf(kk[i]);
            vvp[i] = (short)f2bf(vv[i]);
        }
        __syncthreads();                 // prev chunk's MFMA reads done
        *(s8v*)((char*)kkT + wr_off) = kvp;
        *(s8v*)((char*)vT  + wr_off) = vvp;
        __syncthreads();
        // MFMA over this chunk's 64 rows (2 k-steps of 32)
#pragma unroll
        for (int ks = 0; ks < 2; ++ks) {
            const int G  = ks * 4 + g;           // row granule (8 rows each)
            const int ca = cb  * 16 + li;
            const int c0 = vb0 * 16 + li;
            s8v a  = *(const s8v*)((const char*)kkT + ca * 128 + ((G ^ (ca & 7)) << 4));
            s8v b0 = *(const s8v*)((const char*)vT  + c0 * 128 + ((G ^ (c0 & 7)) << 4));
            s8v b1 = *(const s8v*)((const char*)vT  + (c0 + 16) * 128 + ((G ^ (c0 & 7)) << 4));
            acc0 = __builtin_amdgcn_mfma_f32_16x16x32_bf16(a, b0, acc0, 0, 0, 0);
            acc1 = __builtin_amdgcn_mfma_f32_16x16x32_bf16(a, b1, acc1, 0, 0, 0);
        }
    }
    // write partial ctx tiles: D row = 4*g + r (+cb*16), col = li (+vb*16)
#pragma unroll
    for (int r = 0; r < 4; ++r) {
        const int row = cb * 16 + g * 4 + r;
        ctx_part[blockIdx.x * 4096 + row * 64 + vb0 * 16 + li]       = acc0[r];
        ctx_part[blockIdx.x * 4096 + row * 64 + (vb0 + 1) * 16 + li] = acc1[r];
    }
    qsl[wid * 64 + lane] = qs;
    __syncthreads();
    if (tid < 64) {
        float s = 0.f;
#pragma unroll
        for (int w = 0; w < 8; ++w) s += qsl[w * 64 + tid];
        qs_part[blockIdx.x * 64 + tid] = s;
    }
}

// K2a: reduce column-sum partials -> inv_colsum[64]
__global__ __launch_bounds__(256) void k2a(const float* __restrict__ qs_part,
                                           float* __restrict__ inv_cs) {
    __shared__ float red[4][64];
    const int c = threadIdx.x & 63, g = threadIdx.x >> 6;
    float s = 0.f;
    for (int b = g; b < B1; b += 4) s += qs_part[b * 64 + c];
    red[g][c] = s;
    __syncthreads();
    if (threadIdx.x < 64) {
        float t = (red[0][c] + red[1][c]) + (red[2][c] + red[3][c]);
        inv_cs[c] = 1.0f / t;
    }
}

// K2b: reduce ctx partials, fold inv_colsum, emit ctx TRANSPOSED as bf16:
// ctxfT[v][c] (so k3's B-frags read 8 consecutive c per lane).
__global__ __launch_bounds__(256) void k2b(const float* __restrict__ ctx_part,
                                           const float* __restrict__ inv_cs,
                                           ushort* __restrict__ ctxfT) {
    const int c = blockIdx.x;        // 64 blocks
    const int v = threadIdx.x & 63;
    const int g = threadIdx.x >> 6;  // 0..3
    float s = 0.f;
    for (int b = g; b < B1; b += 4) s += ctx_part[(size_t)b * 4096 + c * 64 + v];
    __shared__ float red[4][64];
    red[g][v] = s;
    __syncthreads();
    if (threadIdx.x < 64) {
        float t = (red[0][v] + red[1][v]) + (red[2][v] + red[3][v]);
        ctxfT[v * 64 + c] = f2bf(t * inv_cs[c]);
    }
}

// K3: out[i][:] = exp2(Q[i][:]*CL) @ ctx'  via MFMA. A-frags straight from
// global Q (8 consecutive cols per lane); B-frags (ctx', 8KB) block-constant.
__global__ __launch_bounds__(256) void k3_out(const float* __restrict__ Q,
                                              const ushort* __restrict__ ctxfT,
                                              float* __restrict__ out) {
    const int tid  = threadIdx.x;
    const int lane = tid & 63;
    const int wid  = tid >> 6;      // 4 waves
    const int li = lane & 15, g = lane >> 4;

    s8v bfr[4][2];
#pragma unroll
    for (int vb = 0; vb < 4; ++vb)
#pragma unroll
        for (int ks = 0; ks < 2; ++ks)
            bfr[vb][ks] = *(const s8v*)((const char*)ctxfT +
                            2 * ((vb * 16 + li) * 64 + 32 * ks + 8 * g));

    for (int t = 0; t < 4; ++t) {
        const int rb  = blockIdx.x * 256 + t * 64 + wid * 16;
        const int row = rb + li;
        const f4v* qp = (const f4v*)(Q + (size_t)row * 64);
        f4v q0 = qp[2 * g], q1 = qp[2 * g + 1];        // cols 8g..8g+7   (ks=0)
        f4v q2 = qp[8 + 2 * g], q3 = qp[8 + 2 * g + 1];// cols 32+8g..+7  (ks=1)
        s8v a0, a1;
#pragma unroll
        for (int e = 0; e < 4; ++e) {
            a0[e]     = (short)f2bf(exp2f(q0[e] * CL));
            a0[e + 4] = (short)f2bf(exp2f(q1[e] * CL));
            a1[e]     = (short)f2bf(exp2f(q2[e] * CL));
            a1[e + 4] = (short)f2bf(exp2f(q3[e] * CL));
        }
#pragma unroll
        for (int vb = 0; vb < 4; ++vb) {
            f4v acc = {0.f, 0.f, 0.f, 0.f};
            acc = __builtin_amdgcn_mfma_f32_16x16x32_bf16(a0, bfr[vb][0], acc, 0, 0, 0);
            acc = __builtin_amdgcn_mfma_f32_16x16x32_bf16(a1, bfr[vb][1], acc, 0, 0, 0);
#pragma unroll
            for (int r = 0; r < 4; ++r)
                out[(size_t)(rb + g * 4 + r) * 64 + vb * 16 + li] = acc[r];
        }
    }
}

extern "C" void kernel_launch(void* const* d_in, const int* in_sizes, int n_in,
                              void* d_out, int out_size, void* d_ws, size_t ws_size,
                              hipStream_t stream) {
    const float* Q = (const float*)d_in[0];
    const float* K = (const float*)d_in[1];
    const float* V = (const float*)d_in[2];
    float* out = (float*)d_out;

    float* w = (float*)d_ws;
    size_t off = 0;
    float*  qs_part = w + off;              off += (size_t)B1 * 64;
    float*  inv_cs  = w + off;              off += 64;
    ushort* ctxfT   = (ushort*)(w + off);   off += 2048;   // 4096 bf16 = 8KB
    float* ctx_part;
    const size_t need = (off + (size_t)B1 * 4096) * sizeof(float);
    if (ws_size >= need) {
        ctx_part = w + off;
    } else {
        // 16.8 MB of partials live in d_out scratch (k3 fully overwrites later)
        ctx_part = out;
    }

    k1_stats<<<B1, 512, 0, stream>>>(Q, K, V, ctx_part, qs_part);
    k2a<<<1, 256, 0, stream>>>(qs_part, inv_cs);
    k2b<<<64, 256, 0, stream>>>(ctx_part, inv_cs, ctxfT);
    k3_out<<<NROWS / 256, 256, 0, stream>>>(Q, ctxfT, out);
}

// Round 3
// 93.877 us; speedup vs baseline: 2.2007x; 2.1510x over previous
//
#include <hip/hip_runtime.h>
#include <hip/hip_bf16.h>

#define NROWS 262144
#define B1 512             // k1 blocks
#define RPB 512            // rows per k1 block
// exp(x*0.125) == exp2(x * 0.125*log2(e))
#define CL 0.18033688011112042f

typedef __attribute__((ext_vector_type(8))) short s8v;   // 8 bf16 (4 VGPRs)
typedef __attribute__((ext_vector_type(4))) float f4v;   // MFMA acc

__device__ __forceinline__ ushort f2bf(float x) {        // RNE float->bf16 bits
    unsigned u = __float_as_uint(x);
    u += 0x7FFF + ((u >> 16) & 1);
    return (ushort)(u >> 16);
}

// sum over each 16-lane group via DPP (VALU pipe, no DS): quad_perm xor1,
// quad_perm xor2, row_half_mirror (sum-of-8), row_mirror (sum-of-16).
__device__ __forceinline__ float dpp_red16(float x) {
    int t;
    t = __builtin_amdgcn_update_dpp(0, __float_as_int(x), 0xB1,  0xF, 0xF, true);
    x += __int_as_float(t);
    t = __builtin_amdgcn_update_dpp(0, __float_as_int(x), 0x4E,  0xF, 0xF, true);
    x += __int_as_float(t);
    t = __builtin_amdgcn_update_dpp(0, __float_as_int(x), 0x141, 0xF, 0xF, true);
    x += __int_as_float(t);
    t = __builtin_amdgcn_update_dpp(0, __float_as_int(x), 0x140, 0xF, 0xF, true);
    x += __int_as_float(t);
    return x;
}

// K1: per block 512 rows. kk = rowsoftmax(K/8) and V staged transposed (bf16,
// XOR-swizzled) in LDS; ctx_part = kk^T @ V via MFMA (each wave owns 2 of the
// 16 16x16 tiles). Also qs_part = partial column sums of exp2(Q*CL).
__global__ __launch_bounds__(512) void k1_stats(const float* __restrict__ Q,
                                                const float* __restrict__ K,
                                                const float* __restrict__ V,
                                                float* __restrict__ ctx_part,  // [B1][4096]
                                                float* __restrict__ qs_part)   // [B1][64]
{
    const int tid  = threadIdx.x;
    const int lane = tid & 63;
    const int wid  = tid >> 6;          // 8 waves
    const int base = blockIdx.x * RPB;

    __shared__ ushort kkT[64 * 64];     // [col c][row r] bf16, swizzled 16B granules
    __shared__ ushort vT [64 * 64];     // [col v][row r]
    __shared__ float  qsl[8 * 64];

    const int cb  = wid >> 1;           // ctx row-block (c)
    const int vb0 = (wid & 1) * 2;      // ctx col-blocks vb0, vb0+1
    f4v acc0 = {0.f, 0.f, 0.f, 0.f};
    f4v acc1 = {0.f, 0.f, 0.f, 0.f};
    float qs = 0.f;

    // write: this wave's 8 rows form LDS granule 'wid' of every column (lane)
    const unsigned wr_off = (unsigned)lane * 128u + (unsigned)((wid ^ (lane & 7)) << 4);
    const int li = lane & 15, g = lane >> 4;

    for (int ch = 0; ch < RPB / 64; ++ch) {
        const int r0 = base + ch * 64 + wid * 8;
        const float* kp = K + (size_t)r0 * 64 + lane;
        const float* vp = V + (size_t)r0 * 64 + lane;
        const float* qp = Q + (size_t)r0 * 64 + lane;
        float kr[8], vr[8], qr[8];
#pragma unroll
        for (int i = 0; i < 8; ++i) kr[i] = kp[i * 64];   // 24 loads hoisted: deep MLP
#pragma unroll
        for (int i = 0; i < 8; ++i) vr[i] = vp[i * 64];
#pragma unroll
        for (int i = 0; i < 8; ++i) qr[i] = qp[i * 64];

        float e[8], s[8];
#pragma unroll
        for (int i = 0; i < 8; ++i) e[i] = exp2f(kr[i] * CL);  // bounded, no max
#pragma unroll
        for (int i = 0; i < 8; ++i) s[i] = dpp_red16(e[i]);    // 8 chains interleaved
#pragma unroll
        for (int i = 0; i < 8; ++i) s[i] += __shfl_xor(s[i], 16);
#pragma unroll
        for (int i = 0; i < 8; ++i) s[i] += __shfl_xor(s[i], 32);

        s8v kvp, vvp;
#pragma unroll
        for (int i = 0; i < 8; ++i) {
            kvp[i] = (short)f2bf(e[i] * __builtin_amdgcn_rcpf(s[i]));
            vvp[i] = (short)f2bf(vr[i]);
            qs += exp2f(qr[i] * CL);     // column-sum partial (lane = column)
        }
        __syncthreads();                 // prev chunk's MFMA reads done
        *(s8v*)((char*)kkT + wr_off) = kvp;
        *(s8v*)((char*)vT  + wr_off) = vvp;
        __syncthreads();
        // MFMA over this chunk's 64 rows (2 k-steps of 32)
#pragma unroll
        for (int ks = 0; ks < 2; ++ks) {
            const int G  = ks * 4 + g;           // row granule (8 rows each)
            const int ca = cb  * 16 + li;
            const int c0 = vb0 * 16 + li;
            s8v a  = *(const s8v*)((const char*)kkT + ca * 128 + ((G ^ (ca & 7)) << 4));
            s8v b0 = *(const s8v*)((const char*)vT  + c0 * 128 + ((G ^ (c0 & 7)) << 4));
            s8v b1 = *(const s8v*)((const char*)vT  + (c0 + 16) * 128 + ((G ^ (c0 & 7)) << 4));
            acc0 = __builtin_amdgcn_mfma_f32_16x16x32_bf16(a, b0, acc0, 0, 0, 0);
            acc1 = __builtin_amdgcn_mfma_f32_16x16x32_bf16(a, b1, acc1, 0, 0, 0);
        }
    }
    // write partial ctx tiles: D row = 4*g + r (+cb*16), col = li (+vb*16)
#pragma unroll
    for (int r = 0; r < 4; ++r) {
        const int row = cb * 16 + g * 4 + r;
        ctx_part[(size_t)blockIdx.x * 4096 + row * 64 + vb0 * 16 + li]       = acc0[r];
        ctx_part[(size_t)blockIdx.x * 4096 + row * 64 + (vb0 + 1) * 16 + li] = acc1[r];
    }
    qsl[wid * 64 + lane] = qs;
    __syncthreads();
    if (tid < 64) {
        float s = 0.f;
#pragma unroll
        for (int w = 0; w < 8; ++w) s += qsl[w * 64 + tid];
        qs_part[blockIdx.x * 64 + tid] = s;
    }
}

// K2: one block per column c. Reduce ctx partials AND Q column-sum partials,
// fold 1/colsum, emit ctx TRANSPOSED bf16: ctxfT[v][c].
__global__ __launch_bounds__(256) void k2(const float* __restrict__ ctx_part,
                                          const float* __restrict__ qs_part,
                                          ushort* __restrict__ ctxfT) {
    const int c = blockIdx.x;        // 64 blocks
    const int tid = threadIdx.x;
    const int v = tid & 63;
    const int g = tid >> 6;          // 0..3
    __shared__ float red[4][64];
    __shared__ float qred[4][64];
    float s = 0.f;
    for (int b = g; b < B1; b += 4) s += ctx_part[(size_t)b * 4096 + c * 64 + v];
    float q = 0.f;
    for (int b = tid; b < B1; b += 256) q += qs_part[b * 64 + c];
    red[g][v] = s;
    qred[g][v] = q;
    __syncthreads();
    if (tid < 64) {
        float t  = (red[0][v] + red[1][v]) + (red[2][v] + red[3][v]);
        float qv = (qred[0][v] + qred[1][v]) + (qred[2][v] + qred[3][v]);
        // all-reduce qv over the 64 lanes (fixed order -> deterministic)
        qv = dpp_red16(qv);
        qv += __shfl_xor(qv, 16);
        qv += __shfl_xor(qv, 32);
        ctxfT[v * 64 + c] = f2bf(t * __builtin_amdgcn_rcpf(qv));
    }
}

// K3: out[i][:] = exp2(Q[i][:]*CL) @ ctx'  via MFMA. A-frags straight from
// global Q (8 consecutive cols per lane); B-frags (ctx', 8KB) block-constant.
__global__ __launch_bounds__(256) void k3_out(const float* __restrict__ Q,
                                              const ushort* __restrict__ ctxfT,
                                              float* __restrict__ out) {
    const int tid  = threadIdx.x;
    const int lane = tid & 63;
    const int wid  = tid >> 6;      // 4 waves
    const int li = lane & 15, g = lane >> 4;

    s8v bfr[4][2];
#pragma unroll
    for (int vb = 0; vb < 4; ++vb)
#pragma unroll
        for (int ks = 0; ks < 2; ++ks)
            bfr[vb][ks] = *(const s8v*)((const char*)ctxfT +
                            2 * ((vb * 16 + li) * 64 + 32 * ks + 8 * g));

#pragma unroll
    for (int t = 0; t < 4; ++t) {   // fully unrolled: loads from all tiles in flight
        const int rb  = blockIdx.x * 256 + t * 64 + wid * 16;
        const int row = rb + li;
        const f4v* qp = (const f4v*)(Q + (size_t)row * 64);
        f4v q0 = qp[2 * g], q1 = qp[2 * g + 1];         // cols 8g..8g+7   (ks=0)
        f4v q2 = qp[8 + 2 * g], q3 = qp[8 + 2 * g + 1]; // cols 32+8g..+7  (ks=1)
        s8v a0, a1;
#pragma unroll
        for (int e = 0; e < 4; ++e) {
            a0[e]     = (short)f2bf(exp2f(q0[e] * CL));
            a0[e + 4] = (short)f2bf(exp2f(q1[e] * CL));
            a1[e]     = (short)f2bf(exp2f(q2[e] * CL));
            a1[e + 4] = (short)f2bf(exp2f(q3[e] * CL));
        }
#pragma unroll
        for (int vb = 0; vb < 4; ++vb) {
            f4v acc = {0.f, 0.f, 0.f, 0.f};
            acc = __builtin_amdgcn_mfma_f32_16x16x32_bf16(a0, bfr[vb][0], acc, 0, 0, 0);
            acc = __builtin_amdgcn_mfma_f32_16x16x32_bf16(a1, bfr[vb][1], acc, 0, 0, 0);
#pragma unroll
            for (int r = 0; r < 4; ++r)
                out[(size_t)(rb + g * 4 + r) * 64 + vb * 16 + li] = acc[r];
        }
    }
}

extern "C" void kernel_launch(void* const* d_in, const int* in_sizes, int n_in,
                              void* d_out, int out_size, void* d_ws, size_t ws_size,
                              hipStream_t stream) {
    const float* Q = (const float*)d_in[0];
    const float* K = (const float*)d_in[1];
    const float* V = (const float*)d_in[2];
    float* out = (float*)d_out;

    float* w = (float*)d_ws;
    size_t off = 0;
    float*  qs_part = w + off;              off += (size_t)B1 * 64;
    ushort* ctxfT   = (ushort*)(w + off);   off += 2048;   // 4096 bf16 = 8KB
    float* ctx_part;
    const size_t need = (off + (size_t)B1 * 4096) * sizeof(float);
    if (ws_size >= need) {
        ctx_part = w + off;
    } else {
        // 8.4 MB of partials live in d_out scratch (k3 fully overwrites later)
        ctx_part = out;
    }

    k1_stats<<<B1, 512, 0, stream>>>(Q, K, V, ctx_part, qs_part);
    k2<<<64, 256, 0, stream>>>(ctx_part, qs_part, ctxfT);
    k3_out<<<NROWS / 256, 256, 0, stream>>>(Q, ctxfT, out);
}

// Round 4
// 92.539 us; speedup vs baseline: 2.2326x; 1.0145x over previous
//
#include <hip/hip_runtime.h>
#include <hip/hip_bf16.h>

#define NROWS 262144
#define B1 512             // k1 blocks
#define RPB 512            // rows per k1 block
// exp(x*0.125) == exp2(x * 0.125*log2(e))
#define CL 0.18033688011112042f

typedef __attribute__((ext_vector_type(8))) short s8v;   // 8 bf16 (4 VGPRs)
typedef __attribute__((ext_vector_type(4))) float f4v;   // MFMA acc

__device__ __forceinline__ ushort f2bf(float x) {        // RNE float->bf16 bits
    unsigned u = __float_as_uint(x);
    u += 0x7FFF + ((u >> 16) & 1);
    return (ushort)(u >> 16);
}

// sum over each 16-lane group via DPP (VALU pipe, no DS): quad_perm xor1,
// quad_perm xor2, row_half_mirror (sum-of-8), row_mirror (sum-of-16).
__device__ __forceinline__ float dpp_red16(float x) {
    int t;
    t = __builtin_amdgcn_update_dpp(0, __float_as_int(x), 0xB1,  0xF, 0xF, true);
    x += __int_as_float(t);
    t = __builtin_amdgcn_update_dpp(0, __float_as_int(x), 0x4E,  0xF, 0xF, true);
    x += __int_as_float(t);
    t = __builtin_amdgcn_update_dpp(0, __float_as_int(x), 0x141, 0xF, 0xF, true);
    x += __int_as_float(t);
    t = __builtin_amdgcn_update_dpp(0, __float_as_int(x), 0x140, 0xF, 0xF, true);
    x += __int_as_float(t);
    return x;
}

// K1: per block 512 rows (8 chunks of 64). Software-pipelined: chunk ch+1's
// 24 global loads are issued into named registers before chunk ch's compute,
// so one chunk of HBM latency hides under softmax+pack+MFMA of the previous.
// LDS staging is double-buffered -> single barrier per chunk.
__global__ __launch_bounds__(512, 4) void k1_stats(const float* __restrict__ Q,
                                                   const float* __restrict__ K,
                                                   const float* __restrict__ V,
                                                   float* __restrict__ ctx_part,  // [B1][4096]
                                                   float* __restrict__ qs_part)   // [B1][64]
{
    const int tid  = threadIdx.x;
    const int lane = tid & 63;
    const int wid  = tid >> 6;          // 8 waves
    const size_t base = (size_t)blockIdx.x * RPB;

    __shared__ ushort kkT[2][64 * 64];  // [buf][col c][row r] bf16, swizzled 16B granules
    __shared__ ushort vT [2][64 * 64];
    __shared__ float  qsl[8 * 64];

    const int cb  = wid >> 1;           // ctx row-block (c)
    const int vb0 = (wid & 1) * 2;      // ctx col-blocks vb0, vb0+1
    f4v acc0 = {0.f, 0.f, 0.f, 0.f};
    f4v acc1 = {0.f, 0.f, 0.f, 0.f};
    float qs = 0.f;

    const unsigned wr_off = (unsigned)lane * 128u + (unsigned)((wid ^ (lane & 7)) << 4);
    const int li = lane & 15, g = lane >> 4;

    const float* kp = K + (base + wid * 8) * 64 + lane;
    const float* vp = V + (base + wid * 8) * 64 + lane;
    const float* qp = Q + (base + wid * 8) * 64 + lane;

    float kr[8], vr[8], qr[8];
#pragma unroll
    for (int i = 0; i < 8; ++i) kr[i] = kp[i * 64];
#pragma unroll
    for (int i = 0; i < 8; ++i) vr[i] = vp[i * 64];
#pragma unroll
    for (int i = 0; i < 8; ++i) qr[i] = qp[i * 64];

    for (int ch = 0; ch < 8; ++ch) {
        // ---- issue next chunk's loads first (hide HBM latency under compute)
        float nkr[8], nvr[8], nqr[8];
        if (ch < 7) {
            const float* kp2 = kp + (size_t)(ch + 1) * 4096;
            const float* vp2 = vp + (size_t)(ch + 1) * 4096;
            const float* qp2 = qp + (size_t)(ch + 1) * 4096;
#pragma unroll
            for (int i = 0; i < 8; ++i) nkr[i] = kp2[i * 64];
#pragma unroll
            for (int i = 0; i < 8; ++i) nvr[i] = vp2[i * 64];
#pragma unroll
            for (int i = 0; i < 8; ++i) nqr[i] = qp2[i * 64];
        }
        // ---- softmax of current chunk (args bounded, no max needed)
        float e[8], s[8];
#pragma unroll
        for (int i = 0; i < 8; ++i) e[i] = exp2f(kr[i] * CL);
#pragma unroll
        for (int i = 0; i < 8; ++i) s[i] = dpp_red16(e[i]);    // 8 chains interleaved
#pragma unroll
        for (int i = 0; i < 8; ++i) s[i] += __shfl_xor(s[i], 16);
#pragma unroll
        for (int i = 0; i < 8; ++i) s[i] += __shfl_xor(s[i], 32);

        s8v kvp, vvp;
#pragma unroll
        for (int i = 0; i < 8; ++i) {
            kvp[i] = (short)f2bf(e[i] * __builtin_amdgcn_rcpf(s[i]));
            vvp[i] = (short)f2bf(vr[i]);
            qs += exp2f(qr[i] * CL);     // column-sum partial (lane = column)
        }
        // ---- stage to LDS buf[p]; single barrier (double-buffered)
        const int p = ch & 1;
        *(s8v*)((char*)kkT[p] + wr_off) = kvp;
        *(s8v*)((char*)vT[p]  + wr_off) = vvp;
        __syncthreads();
        // ---- MFMA over this chunk's 64 rows (2 k-steps of 32)
#pragma unroll
        for (int ks = 0; ks < 2; ++ks) {
            const int G  = ks * 4 + g;           // row granule (8 rows each)
            const int ca = cb  * 16 + li;
            const int c0 = vb0 * 16 + li;
            s8v a  = *(const s8v*)((const char*)kkT[p] + ca * 128 + ((G ^ (ca & 7)) << 4));
            s8v b0 = *(const s8v*)((const char*)vT[p]  + c0 * 128 + ((G ^ (c0 & 7)) << 4));
            s8v b1 = *(const s8v*)((const char*)vT[p]  + (c0 + 16) * 128 + ((G ^ (c0 & 7)) << 4));
            acc0 = __builtin_amdgcn_mfma_f32_16x16x32_bf16(a, b0, acc0, 0, 0, 0);
            acc1 = __builtin_amdgcn_mfma_f32_16x16x32_bf16(a, b1, acc1, 0, 0, 0);
        }
        // ---- rotate pipeline registers
        if (ch < 7) {
#pragma unroll
            for (int i = 0; i < 8; ++i) { kr[i] = nkr[i]; vr[i] = nvr[i]; qr[i] = nqr[i]; }
        }
    }
    // write partial ctx tiles: D row = 4*g + r (+cb*16), col = li (+vb*16)
#pragma unroll
    for (int r = 0; r < 4; ++r) {
        const int row = cb * 16 + g * 4 + r;
        ctx_part[(size_t)blockIdx.x * 4096 + row * 64 + vb0 * 16 + li]       = acc0[r];
        ctx_part[(size_t)blockIdx.x * 4096 + row * 64 + (vb0 + 1) * 16 + li] = acc1[r];
    }
    qsl[wid * 64 + lane] = qs;
    __syncthreads();
    if (tid < 64) {
        float s = 0.f;
#pragma unroll
        for (int w = 0; w < 8; ++w) s += qsl[w * 64 + tid];
        qs_part[blockIdx.x * 64 + tid] = s;
    }
}

// K2: one block per column c. Reduce ctx partials AND Q column-sum partials,
// fold 1/colsum, emit ctx TRANSPOSED bf16: ctxfT[v][c].
__global__ __launch_bounds__(256) void k2(const float* __restrict__ ctx_part,
                                          const float* __restrict__ qs_part,
                                          ushort* __restrict__ ctxfT) {
    const int c = blockIdx.x;        // 64 blocks
    const int tid = threadIdx.x;
    const int v = tid & 63;
    const int g = tid >> 6;          // 0..3
    __shared__ float red[4][64];
    __shared__ float qred[4][64];
    float s = 0.f;
    for (int b = g; b < B1; b += 4) s += ctx_part[(size_t)b * 4096 + c * 64 + v];
    float q = 0.f;
    for (int b = tid; b < B1; b += 256) q += qs_part[b * 64 + c];
    red[g][v] = s;
    qred[g][v] = q;
    __syncthreads();
    if (tid < 64) {
        float t  = (red[0][v] + red[1][v]) + (red[2][v] + red[3][v]);
        float qv = (qred[0][v] + qred[1][v]) + (qred[2][v] + qred[3][v]);
        qv = dpp_red16(qv);
        qv += __shfl_xor(qv, 16);
        qv += __shfl_xor(qv, 32);
        ctxfT[v * 64 + c] = f2bf(t * __builtin_amdgcn_rcpf(qv));
    }
}

// K3: out[i][:] = exp2(Q[i][:]*CL) @ ctx'  via MFMA. A-frags straight from
// global Q (8 consecutive cols per lane); B-frags (ctx', 8KB) block-constant.
__global__ __launch_bounds__(256) void k3_out(const float* __restrict__ Q,
                                              const ushort* __restrict__ ctxfT,
                                              float* __restrict__ out) {
    const int tid  = threadIdx.x;
    const int lane = tid & 63;
    const int wid  = tid >> 6;      // 4 waves
    const int li = lane & 15, g = lane >> 4;

    s8v bfr[4][2];
#pragma unroll
    for (int vb = 0; vb < 4; ++vb)
#pragma unroll
        for (int ks = 0; ks < 2; ++ks)
            bfr[vb][ks] = *(const s8v*)((const char*)ctxfT +
                            2 * ((vb * 16 + li) * 64 + 32 * ks + 8 * g));

#pragma unroll
    for (int t = 0; t < 4; ++t) {   // fully unrolled: loads from all tiles in flight
        const int rb  = blockIdx.x * 256 + t * 64 + wid * 16;
        const int row = rb + li;
        const f4v* qp = (const f4v*)(Q + (size_t)row * 64);
        f4v q0 = qp[2 * g], q1 = qp[2 * g + 1];         // cols 8g..8g+7   (ks=0)
        f4v q2 = qp[8 + 2 * g], q3 = qp[8 + 2 * g + 1]; // cols 32+8g..+7  (ks=1)
        s8v a0, a1;
#pragma unroll
        for (int e = 0; e < 4; ++e) {
            a0[e]     = (short)f2bf(exp2f(q0[e] * CL));
            a0[e + 4] = (short)f2bf(exp2f(q1[e] * CL));
            a1[e]     = (short)f2bf(exp2f(q2[e] * CL));
            a1[e + 4] = (short)f2bf(exp2f(q3[e] * CL));
        }
#pragma unroll
        for (int vb = 0; vb < 4; ++vb) {
            f4v acc = {0.f, 0.f, 0.f, 0.f};
            acc = __builtin_amdgcn_mfma_f32_16x16x32_bf16(a0, bfr[vb][0], acc, 0, 0, 0);
            acc = __builtin_amdgcn_mfma_f32_16x16x32_bf16(a1, bfr[vb][1], acc, 0, 0, 0);
#pragma unroll
            for (int r = 0; r < 4; ++r)
                out[(size_t)(rb + g * 4 + r) * 64 + vb * 16 + li] = acc[r];
        }
    }
}

extern "C" void kernel_launch(void* const* d_in, const int* in_sizes, int n_in,
                              void* d_out, int out_size, void* d_ws, size_t ws_size,
                              hipStream_t stream) {
    const float* Q = (const float*)d_in[0];
    const float* K = (const float*)d_in[1];
    const float* V = (const float*)d_in[2];
    float* out = (float*)d_out;

    float* w = (float*)d_ws;
    size_t off = 0;
    float*  qs_part = w + off;              off += (size_t)B1 * 64;
    ushort* ctxfT   = (ushort*)(w + off);   off += 2048;   // 4096 bf16 = 8KB
    float* ctx_part;
    const size_t need = (off + (size_t)B1 * 4096) * sizeof(float);
    if (ws_size >= need) {
        ctx_part = w + off;
    } else {
        // 8.4 MB of partials live in d_out scratch (k3 fully overwrites later)
        ctx_part = out;
    }

    k1_stats<<<B1, 512, 0, stream>>>(Q, K, V, ctx_part, qs_part);
    k2<<<64, 256, 0, stream>>>(ctx_part, qs_part, ctxfT);
    k3_out<<<NROWS / 256, 256, 0, stream>>>(Q, ctxfT, out);
}